// Round 1
// baseline (754.222 us; speedup 1.0000x reference)
//
#include <hip/hip_runtime.h>

#define KVOX 12000
#define TPTS 35
#define FIN  7
#define DD   10
#define HH   400
#define WW   352
#define CO   128
#define EPSBN 1e-3f

__global__ __launch_bounds__(64) void vfe_scatter(
    const float* __restrict__ feat,
    const float* __restrict__ w1, const float* __restrict__ b1,
    const float* __restrict__ g1, const float* __restrict__ be1,
    const float* __restrict__ m1, const float* __restrict__ v1,
    const float* __restrict__ w2, const float* __restrict__ b2,
    const float* __restrict__ g2, const float* __restrict__ be2,
    const float* __restrict__ m2, const float* __restrict__ v2,
    const int* __restrict__ coord,
    float* __restrict__ out)
{
    const int k   = blockIdx.x;
    const int tid = threadIdx.x;

    __shared__ float sx[TPTS][FIN];                 // raw point features
    __shared__ float smask[TPTS];                   // 0/1 validity mask
    __shared__ __align__(16) float sx2[TPTS][32];   // stage-2 input (masked cat1)

    // ---- load features (245 floats, coalesced) ----
    const float* fk = feat + (size_t)k * (TPTS * FIN);
    for (int i = tid; i < TPTS * FIN; i += 64)
        ((float*)sx)[i] = fk[i];
    __syncthreads();

    // ---- mask per point: (max over F features) != 0 ----
    bool pred = false;
    if (tid < TPTS) {
        float mx = sx[tid][0];
        #pragma unroll
        for (int f = 1; f < FIN; ++f) mx = fmaxf(mx, sx[tid][f]);
        pred = (mx != 0.0f);
        smask[tid] = pred ? 1.0f : 0.0f;
    }
    unsigned long long bal = __ballot(pred);
    const int nvalid = __popcll(bal);
    __syncthreads();

    // ---- stage 1: dense(7->16) + relu + BN, agg max over ALL t, masked concat ----
    if (tid < 16) {
        const int u = tid;
        float w1c[FIN];
        #pragma unroll
        for (int f = 0; f < FIN; ++f) w1c[f] = w1[f * 16 + u];
        const float b     = b1[u];
        const float scale = g1[u] * rsqrtf(v1[u] + EPSBN);
        const float shift = be1[u] - m1[u] * scale;

        float agg = -INFINITY;
        float pw[TPTS];
        #pragma unroll
        for (int t = 0; t < TPTS; ++t) {
            float d = b;
            #pragma unroll
            for (int f = 0; f < FIN; ++f) d = fmaf(sx[t][f], w1c[f], d);
            d = fmaxf(d, 0.0f);                 // relu
            float p = fmaf(d, scale, shift);    // BN
            agg = fmaxf(agg, p);                // max over all t (incl. padded rows)
            pw[t] = p;
        }
        #pragma unroll
        for (int t = 0; t < TPTS; ++t) {
            const float mk = smask[t];
            sx2[t][u]      = pw[t] * mk;        // pointwise part, masked
            sx2[t][16 + u] = agg   * mk;        // tiled aggregate, masked
        }
    }
    __syncthreads();

    // ---- stage 2: dense(32->64) + relu + BN, channel v per lane ----
    {
        const int v = tid;  // 0..63
        float w2c[32];
        #pragma unroll
        for (int u = 0; u < 32; ++u) w2c[u] = w2[u * 64 + v];
        const float b     = b2[v];
        const float scale = g2[v] * rsqrtf(v2[v] + EPSBN);
        const float shift = be2[v] - m2[v] * scale;

        float aggAll = -INFINITY;   // max over ALL t of pw2 (for concat half)
        float voxA   = -INFINITY;   // max over t of pw2*mask (pointwise half)
        #pragma unroll 5
        for (int t = 0; t < TPTS; ++t) {
            float d = b;
            const float4* xr = (const float4*)(&sx2[t][0]);
            #pragma unroll
            for (int q = 0; q < 8; ++q) {
                float4 xv = xr[q];   // same-address broadcast across the wave
                d = fmaf(xv.x, w2c[4 * q + 0], d);
                d = fmaf(xv.y, w2c[4 * q + 1], d);
                d = fmaf(xv.z, w2c[4 * q + 2], d);
                d = fmaf(xv.w, w2c[4 * q + 3], d);
            }
            d = fmaxf(d, 0.0f);
            float p = fmaf(d, scale, shift);
            aggAll = fmaxf(aggAll, p);
            voxA   = fmaxf(voxA, p * smask[t]);
        }
        // voxelwise for concat-aggregate half: max over t of aggAll*mask[t]
        float voxB;
        if (nvalid == 0)          voxB = 0.0f;
        else if (nvalid < TPTS)   voxB = fmaxf(aggAll, 0.0f);
        else                      voxB = aggAll;

        // ---- scatter-add (tf.scatter_nd: duplicates accumulate) ----
        const int4 c = ((const int4*)coord)[k];
        const int loc = (((c.x * DD + c.y) * HH + c.z) * WW + c.w);
        float* o = out + (size_t)loc * CO;
        atomicAdd(o + v,      voxA);
        atomicAdd(o + 64 + v, voxB);
    }
}

extern "C" void kernel_launch(void* const* d_in, const int* in_sizes, int n_in,
                              void* d_out, int out_size, void* d_ws, size_t ws_size,
                              hipStream_t stream) {
    const float* feat = (const float*)d_in[0];
    const float* w1   = (const float*)d_in[1];
    const float* b1   = (const float*)d_in[2];
    const float* g1   = (const float*)d_in[3];
    const float* be1  = (const float*)d_in[4];
    const float* m1   = (const float*)d_in[5];
    const float* v1   = (const float*)d_in[6];
    const float* w2   = (const float*)d_in[7];
    const float* b2   = (const float*)d_in[8];
    const float* g2   = (const float*)d_in[9];
    const float* be2  = (const float*)d_in[10];
    const float* m2   = (const float*)d_in[11];
    const float* v2   = (const float*)d_in[12];
    const int*   coord = (const int*)d_in[13];
    float* out = (float*)d_out;

    // Output is poisoned to 0xAA before every timed call: full zero-fill required.
    hipMemsetAsync(d_out, 0, (size_t)out_size * sizeof(float), stream);

    vfe_scatter<<<KVOX, 64, 0, stream>>>(feat, w1, b1, g1, be1, m1, v1,
                                         w2, b2, g2, be2, m2, v2, coord, out);
}